// Round 1
// 59.869 us; speedup vs baseline: 1.0230x; 1.0230x over previous
//
#include <hip/hip_runtime.h>

// Problem constants (B=8, U=512, F=64, R=256)
#define BU   4096      // B*U rows of x
#define F_   64
#define R_   256
#define ROWS 16        // x-rows per block; grid = BU/ROWS = 256 blocks

// fp64 -> fp32 with flush-to-zero for denormal results, matching the
// XLA/GPU fp32 reference semantics (f32 denormals flushed). d >= 0.
// Every factor <= 1 so the reference's running product is non-increasing;
// "final < FLT_MIN => reference produced 0" holds exactly.
__device__ __forceinline__ float d2f_ftz(double d) {
    return (d >= 0x1.0p-126) ? (float)d : 0.0f;
}

// out[bu, r] = (prod_f x[bu,f]) * (prod_f rules[r,f])   (separable product)
//
// 512 threads/block:
//   waves 0-3 (t <  256): Pr[t] = prod_f rules[t][f], 4 independent fp64
//                         sub-chains of 16 (chain depth ~18 vs 64).
//   waves 4-7 (t >= 256): Px[row] for the block's 16 rows, 16 lanes/row:
//                         float4 load + 3-mul tree + 4-step shfl_xor
//                         butterfly (chain depth ~9). Runs CONCURRENTLY
//                         with the Pr waves -> 2 waves/SIMD of overlap.
// Epilogue: lane c owns columns {c, c+64, c+128, c+192} so the sPr
// double reads are 4-way banked (the b64 floor) instead of 16-way, and
// global stores stay fully coalesced (64 consecutive dwords / inst).
__global__ __launch_bounds__(512) void rules_outer_kernel(
        const float* __restrict__ x,        // [BU, F]
        const float* __restrict__ rules,    // [R, F]
        float* __restrict__ out)            // [BU, R]
{
    __shared__ double sPr[R_];
    __shared__ double sPx[ROWS];

    const int t   = threadIdx.x;            // 0..511
    const int bu0 = blockIdx.x * ROWS;

    if (t < R_) {
        // ---- per-rule product, 4 independent chains ----
        const float4* rp = (const float4*)(rules + (size_t)t * F_);
        double p0 = 1.0, p1 = 1.0, p2 = 1.0, p3 = 1.0;
        #pragma unroll
        for (int i = 0; i < F_ / 4; ++i) {
            float4 v = rp[i];
            p0 *= (double)v.x;
            p1 *= (double)v.y;
            p2 *= (double)v.z;
            p3 *= (double)v.w;
        }
        sPr[t] = (p0 * p1) * (p2 * p3);
    } else {
        // ---- per-row product, 16 lanes per row ----
        const int s   = t - R_;             // 0..255
        const int row = s >> 4;             // 0..15
        const int q   = s & 15;             // 0..15
        float4 v = ((const float4*)(x + (size_t)(bu0 + row) * F_))[q];
        double p = ((double)v.x * (double)v.y) * ((double)v.z * (double)v.w);
        // butterfly product across the 16-lane group (masks < 16 stay
        // within the group; 64-lane wave => 4 groups reduce in parallel)
        p *= __shfl_xor(p, 1);
        p *= __shfl_xor(p, 2);
        p *= __shfl_xor(p, 4);
        p *= __shfl_xor(p, 8);
        if (q == 0) sPx[row] = p;
    }
    __syncthreads();

    // ---- outer product tile: 16 rows x 256 cols, 512 threads ----
    const int c    = t & 63;                // column within group of 64
    const int wrow = t >> 6;                // 0..7
    // strided columns: 4-way LDS banking (lanes c, c+16, c+32, c+48 share)
    const double pr0 = sPr[c];
    const double pr1 = sPr[c + 64];
    const double pr2 = sPr[c + 128];
    const double pr3 = sPr[c + 192];

    #pragma unroll
    for (int pass = 0; pass < 2; ++pass) {
        const int row = wrow + pass * 8;
        const double px = sPx[row];         // wave-uniform -> LDS broadcast
        float* op = out + (size_t)(bu0 + row) * R_ + c;
        op[0]   = d2f_ftz(px * pr0);        // 64 consecutive dwords / wave
        op[64]  = d2f_ftz(px * pr1);
        op[128] = d2f_ftz(px * pr2);
        op[192] = d2f_ftz(px * pr3);
    }
}

extern "C" void kernel_launch(void* const* d_in, const int* in_sizes, int n_in,
                              void* d_out, int out_size, void* d_ws, size_t ws_size,
                              hipStream_t stream) {
    const float* x     = (const float*)d_in[0];   // [8,512,64]
    const float* rules = (const float*)d_in[1];   // [256,64]
    // d_in[2] = epoch (unused)
    float* out = (float*)d_out;                   // [8,512,256]

    rules_outer_kernel<<<BU / ROWS, 512, 0, stream>>>(x, rules, out);
}